// Round 2
// baseline (485.935 us; speedup 1.0000x reference)
//
#include <hip/hip_runtime.h>
#include <hip/hip_bf16.h>
#include <math.h>

// Problem constants (B=4, S=2048 -> T=8192, D=1024, E=8, K=2, H=2048)
#define T_TOK 8192
#define D_DIM 1024
#define E_NUM 8
#define H_DIM 2048

typedef __bf16 bf16;
typedef __bf16 bf16x8 __attribute__((ext_vector_type(8)));
typedef __bf16 bf16x4 __attribute__((ext_vector_type(4)));
typedef float  f32x4  __attribute__((ext_vector_type(4)));

// async global->LDS, 16 B per lane; LDS dest = wave-uniform base + lane*16
__device__ __forceinline__ void gload_lds16(const void* g, void* s) {
    __builtin_amdgcn_global_load_lds(
        (const __attribute__((address_space(1))) unsigned int*)g,
        (__attribute__((address_space(3))) unsigned int*)s, 16, 0, 0);
}

// raw barrier / counted waits (8-phase schedule manages its own drains;
// never vmcnt(0) in the main loop)
#define BAR()        asm volatile("s_barrier" ::: "memory")
#define WAIT_LGKM0() do { asm volatile("s_waitcnt lgkmcnt(0)" ::: "memory"); \
                          __builtin_amdgcn_sched_barrier(0); } while (0)
#define WAIT_VM(n)   asm volatile("s_waitcnt vmcnt(" #n ")" ::: "memory")

// ---------------------------------------------------------------- transpose
// W [E][K][N] fp32  ->  Wt [E][N][K] bf16.  32x32 tiles via LDS.
template <int K, int N>
__global__ void transpose_kernel(const float* __restrict__ W, bf16* __restrict__ Wt) {
    const int e  = blockIdx.z;
    const int kb = blockIdx.y * 32;
    const int nb = blockIdx.x * 32;
    __shared__ float tile[32][33];
    const float* We  = W  + (size_t)e * K * N;
    bf16*        Wte = Wt + (size_t)e * N * K;
    const int tid = threadIdx.x;
    const int r  = tid >> 3;        // 0..31
    const int c4 = (tid & 7) * 4;   // 0..28
    float4 v = *(const float4*)(We + (size_t)(kb + r) * N + nb + c4);
    tile[r][c4 + 0] = v.x; tile[r][c4 + 1] = v.y;
    tile[r][c4 + 2] = v.z; tile[r][c4 + 3] = v.w;
    __syncthreads();
    const int rn = tid >> 3;        // n within tile
    const int k4 = (tid & 7) * 4;   // k within tile
    bf16x4 o;
    o[0] = (bf16)tile[k4 + 0][rn]; o[1] = (bf16)tile[k4 + 1][rn];
    o[2] = (bf16)tile[k4 + 2][rn]; o[3] = (bf16)tile[k4 + 3][rn];
    *(bf16x4*)(Wte + (size_t)(nb + rn) * K + kb + k4) = o;
}

// ---------------------------------------------------------------- gating
// Block = 4 waves = 4 tokens. Lane l: expert e = l&7, d-slice s = l>>3.
// Also writes the bf16 copy of x (fused cvt_x: x rows are already staged in
// LDS here, so the separate 48 MB cvt pass is free).
__global__ __launch_bounds__(256) void gating_kernel(
    const float* __restrict__ x, const float* __restrict__ gw,
    const float* __restrict__ gb, bf16* __restrict__ xb,
    int* __restrict__ eIdx, float* __restrict__ wgt) {
    __shared__ float xs[4 * D_DIM];
    const int tid  = threadIdx.x;
    const int wave = tid >> 6;
    const int lane = tid & 63;
    {
        const float4* src = (const float4*)(x + (size_t)blockIdx.x * 4 * D_DIM);
        float4* dst = (float4*)xs;
#pragma unroll
        for (int k = 0; k < 4; k++) dst[tid + k * 256] = src[tid + k * 256];
    }
    __syncthreads();

    // fused bf16 conversion: 16 elements per thread
    {
        bf16* xbp = xb + (size_t)blockIdx.x * 4 * D_DIM;
        const float* s = xs + tid * 16;
        bf16x8 o0, o1;
#pragma unroll
        for (int q = 0; q < 8; q++) { o0[q] = (bf16)s[q]; o1[q] = (bf16)s[8 + q]; }
        *(bf16x8*)(xbp + tid * 16)     = o0;
        *(bf16x8*)(xbp + tid * 16 + 8) = o1;
    }

    const int e = lane & 7;
    const int s = lane >> 3;
    const float* xw = xs + wave * D_DIM;
    double acc_a = 0.0, acc_b = 0.0;
#pragma unroll 8
    for (int i = 0; i < 128; i += 2) {
        int d0 = i * 8 + s;
        int d1 = (i + 1) * 8 + s;
        acc_a += (double)xw[d0] * (double)gw[d0 * 8 + e];
        acc_b += (double)xw[d1] * (double)gw[d1 * 8 + e];
    }
    double acc = acc_a + acc_b;
    acc += __shfl_xor(acc, 8, 64);
    acc += __shfl_xor(acc, 16, 64);
    acc += __shfl_xor(acc, 32, 64);
    double lg[E_NUM];
#pragma unroll
    for (int k = 0; k < E_NUM; k++) lg[k] = __shfl(acc, k, 64);

    if (lane == 0) {
        int token = blockIdx.x * 4 + wave;
        double v[E_NUM], p[E_NUM];
        double mx = -1e300;
#pragma unroll
        for (int k = 0; k < E_NUM; k++) { v[k] = lg[k] + (double)gb[k]; mx = fmax(mx, v[k]); }
        double sum = 0.0;
#pragma unroll
        for (int k = 0; k < E_NUM; k++) { p[k] = exp(v[k] - mx); sum += p[k]; }
        int i0 = 0; double p0 = p[0];
#pragma unroll
        for (int k = 1; k < E_NUM; k++) if (p[k] > p0) { p0 = p[k]; i0 = k; }
        int i1 = -1; double p1 = -1.0;
#pragma unroll
        for (int k = 0; k < E_NUM; k++) if (k != i0 && p[k] > p1) { p1 = p[k]; i1 = k; }
        double q0 = p0 / sum, q1 = p1 / sum;
        double sw = q0 + q1 + 1e-9;
        eIdx[token * 2]     = i0;
        eIdx[token * 2 + 1] = i1;
        wgt[token * 2]      = (float)(q0 / sw);
        wgt[token * 2 + 1]  = (float)(q1 / sw);
    }
}

// ---------------------------------------------------------------- count
__global__ void count_kernel(const int* __restrict__ eIdx, int* __restrict__ counts) {
    __shared__ int bc[E_NUM];
    const int tid = threadIdx.x;
    if (tid < E_NUM) bc[tid] = 0;
    __syncthreads();
    int2 ev = *(const int2*)(eIdx + (size_t)blockIdx.x * 512 + tid * 2);
    atomicAdd(&bc[ev.x], 1);
    atomicAdd(&bc[ev.y], 1);
    __syncthreads();
    if (tid < E_NUM) atomicAdd(&counts[tid], bc[tid]);
}

// ---------------------------------------------------------------- scan
__global__ void scan_kernel(const int* __restrict__ counts, int* __restrict__ offsets) {
    if (threadIdx.x == 0) {
        int s = 0;
        for (int e = 0; e < E_NUM; e++) { offsets[e] = s; s += counts[e]; }
    }
}

// ---------------------------------------------------------------- scatter
__global__ void scatter_kernel(const int* __restrict__ eIdx, const int* __restrict__ offsets,
                               int* __restrict__ fill, int* __restrict__ rowIdx,
                               int* __restrict__ slot) {
    __shared__ int bc[E_NUM];
    __shared__ int bbase[E_NUM];
    __shared__ int bcur[E_NUM];
    const int tid = threadIdx.x;
    if (tid < E_NUM) { bc[tid] = 0; bcur[tid] = 0; }
    __syncthreads();
    int t0 = blockIdx.x * 512 + tid * 2;  // two tokens per thread
    int4 ev = *(const int4*)(eIdx + (size_t)t0 * 2);
    atomicAdd(&bc[ev.x], 1);
    atomicAdd(&bc[ev.y], 1);
    atomicAdd(&bc[ev.z], 1);
    atomicAdd(&bc[ev.w], 1);
    __syncthreads();
    if (tid < E_NUM) bbase[tid] = atomicAdd(&fill[tid], bc[tid]);
    __syncthreads();
    int p0 = atomicAdd(&bcur[ev.x], 1);
    int r0 = offsets[ev.x] + bbase[ev.x] + p0;
    rowIdx[r0] = t0; slot[t0 * 2] = r0;
    int p1 = atomicAdd(&bcur[ev.y], 1);
    int r1 = offsets[ev.y] + bbase[ev.y] + p1;
    rowIdx[r1] = t0; slot[t0 * 2 + 1] = r1;
    int p2 = atomicAdd(&bcur[ev.z], 1);
    int r2 = offsets[ev.z] + bbase[ev.z] + p2;
    rowIdx[r2] = t0 + 1; slot[(t0 + 1) * 2] = r2;
    int p3 = atomicAdd(&bcur[ev.w], 1);
    int r3 = offsets[ev.w] + bbase[ev.w] + p3;
    rowIdx[r3] = t0 + 1; slot[(t0 + 1) * 2 + 1] = r3;
}

// ---------------------------------------------------------------- grouped GEMM (256x256, 8-phase)
// T2+T3+T4+T5 stack: 256x256 tile, BK=64, 8 waves (2M x 4N), 128 KiB
// double-buffered LDS, per-phase {ds_read subtile || stage 1 half-tile ->
// barrier -> lgkmcnt(0) -> setprio(1) MFMA setprio(0) -> barrier},
// counted vmcnt(4) only at K-tile boundaries.
//
// LDS layout: [row][64] bf16, XOR-swizzled: elem-col ^= (row&7)<<3 (byte bits
// 4-6). global_load_lds dest stays LINEAR; the global SOURCE address is
// pre-swizzled per lane (rule #21: both-sides-or-neither). ds_read_b128 of a
// fragment: slot index c3 = (ks*4+quad)^(lrow&7) takes each of 8 values on
// exactly 8 lanes -> 8 bank-groups x 8 lanes = the structural 8-cycle floor
// for a wave64 b128 read (vs 16 cycles unswizzled 16-way conflict).
//
// Staging liveness (ledger-verified):
//   B-half h of buf is fully read by end of ph(h?1:0)+1: readers drain at
//   that phase's lgkmcnt(0), which precedes the phase-end s_barrier, which
//   precedes any wave's ph2/ph3 in-place STAGE_B(k+2). A halves drain at
//   ph2's lgkmcnt(0); A(k+1) stages into the OTHER buffer whose readers
//   finished during tile k-1.
// vmcnt induction (steady state, per wave): at each K-tile boundary the
// queue is 12 deep: [B(k+1)x4 (issued tile k-1 ph2/3), A(k+1)x4 (ph0/1),
// B(k+2)x4 (ph2/3)]. WAIT_VM(4) drains the oldest 8 = B(k+1)+A(k+1) --
// exactly what tile k+1 ph0 reads -- leaving B(k+2) in flight. Prologue
// queue [A0x4,B0x4,B1x4] -> WAIT_VM(4) drains ktile0. Last two tiles
// stage less and drain with vmcnt(0).
template <int KD, int ND, bool RELU, bool GATHER>
__global__ __launch_bounds__(512, 2) void moe_gemm256_kernel(
    const bf16* __restrict__ A, const bf16* __restrict__ Bt,
    const float* __restrict__ bias, bf16* __restrict__ Out,
    const int* __restrict__ counts, const int* __restrict__ offsets,
    const int* __restrict__ rowIdx) {
    constexpr int NK = KD / 64;          // 16 (GEMM1) or 32 (GEMM2)
    const int e  = blockIdx.z;
    const int Ne = counts[e];
    const int rb = blockIdx.y;
    if (rb * 256 >= Ne) return;
    const int base = offsets[e];
    const int n0   = blockIdx.x * 256;
    const bf16*  Be = Bt + (size_t)e * KD * ND;  // [ND][KD]
    const float* be = bias + (size_t)e * ND;

    __shared__ __attribute__((aligned(16))) bf16 As[2 * 16384];  // 64 KiB
    __shared__ __attribute__((aligned(16))) bf16 Bs[2 * 16384];  // 64 KiB

    const int tid  = threadIdx.x;
    const int wid  = tid >> 6;
    const int lane = tid & 63;
    const int lrow = lane & 15;
    const int quad = lane >> 4;
    const int wm   = (wid >> 2) * 128;   // WARPS_M = 2
    const int wn   = (wid & 3) * 64;     // WARPS_N = 4
    const int rsw  = (lrow & 7) << 3;    // read-side swizzle (elements)

    // ---- staging geometry: thread covers LDS elems (wid*2+j)*512 + lane*8
    // within a 128x64 half-tile -> row r = (wid*2+j)*8 + lane/8, col (lane&7)*8.
    // Global source col is pre-swizzled: (lane&7)*8 ^ ((r&7)<<3), r&7 = lane>>3.
    const int csw = ((lane & 7) * 8) ^ ((lane >> 3) << 3);
    const bf16* srcA[2][2];
    const bf16* srcB[2][2];
#pragma unroll
    for (int h = 0; h < 2; h++) {
#pragma unroll
        for (int j = 0; j < 2; j++) {
            int r  = h * 128 + (wid * 2 + j) * 8 + (lane >> 3);
            int gm = rb * 256 + r;
            if (gm >= Ne) gm = Ne - 1;  // tail rows: stage a valid row, mask store
            size_t arow = GATHER ? (size_t)rowIdx[base + gm] : (size_t)(base + gm);
            srcA[h][j] = A + arow * KD + csw;
            srcB[h][j] = Be + (size_t)(n0 + r) * KD + csw;
        }
    }

#define STAGE_A(bufi, h, kofs) do { \
    gload_lds16(srcA[h][0] + (kofs), &As[(bufi) * 16384 + (h) * 8192 + (wid * 2 + 0) * 512]); \
    gload_lds16(srcA[h][1] + (kofs), &As[(bufi) * 16384 + (h) * 8192 + (wid * 2 + 1) * 512]); } while (0)
#define STAGE_B(bufi, h, kofs) do { \
    gload_lds16(srcB[h][0] + (kofs), &Bs[(bufi) * 16384 + (h) * 8192 + (wid * 2 + 0) * 512]); \
    gload_lds16(srcB[h][1] + (kofs), &Bs[(bufi) * 16384 + (h) * 8192 + (wid * 2 + 1) * 512]); } while (0)
#define READ_A(dst, bufi, mh, ti, ks) do { \
    const int row_ = wm + (mh) * 64 + (ti) * 16 + lrow; \
    dst = *(const bf16x8*)&As[(bufi) * 16384 + row_ * 64 + (((ks) * 32 + quad * 8) ^ rsw)]; } while (0)
#define READ_B(dst, bufi, nh, tj, ks) do { \
    const int row_ = wn + (nh) * 32 + (tj) * 16 + lrow; \
    dst = *(const bf16x8*)&Bs[(bufi) * 16384 + row_ * 64 + (((ks) * 32 + quad * 8) ^ rsw)]; } while (0)

    f32x4 acc[8][4] = {};      // [mh*4+ti][nh*2+tj]
    bf16x8 a[4][2];            // A frags, reused mh0 -> mh1
    bf16x8 bv0[2][2], bv1[2][2];

    // ---- prologue: ktile0 (A0,A1,B0,B1) + B halves of ktile1
    STAGE_A(0, 0, 0); STAGE_A(0, 1, 0);
    STAGE_B(0, 0, 0); STAGE_B(0, 1, 0);
    STAGE_B(1, 0, 64); STAGE_B(1, 1, 64);
    WAIT_VM(4);   // ktile0's 8 loads done; B(1) (4) stays in flight
    BAR();

#pragma unroll 2
    for (int k = 0; k < NK; ++k) {
        const int buf = k & 1, nbuf = buf ^ 1;
        const int kA = (k + 1) * 64;
        const int kB = (k + 2) * 64;

        // ---- phase 0: quadrant (mh0, nh0); 12 ds_reads; stage A0(k+1)
#pragma unroll
        for (int ti = 0; ti < 4; ti++)
#pragma unroll
            for (int ks = 0; ks < 2; ks++) READ_A(a[ti][ks], buf, 0, ti, ks);
#pragma unroll
        for (int tj = 0; tj < 2; tj++)
#pragma unroll
            for (int ks = 0; ks < 2; ks++) READ_B(bv0[tj][ks], buf, 0, tj, ks);
        if (k + 1 < NK) STAGE_A(nbuf, 0, kA);
        BAR(); WAIT_LGKM0();
        __builtin_amdgcn_s_setprio(1);
#pragma unroll
        for (int ks = 0; ks < 2; ks++)
#pragma unroll
            for (int ti = 0; ti < 4; ti++)
#pragma unroll
                for (int tj = 0; tj < 2; tj++)
                    acc[ti][tj] = __builtin_amdgcn_mfma_f32_16x16x32_bf16(
                        a[ti][ks], bv0[tj][ks], acc[ti][tj], 0, 0, 0);
        __builtin_amdgcn_s_setprio(0);
        __builtin_amdgcn_sched_barrier(0);
        BAR();

        // ---- phase 1: (mh0, nh1); 4 ds_reads; stage A1(k+1)
#pragma unroll
        for (int tj = 0; tj < 2; tj++)
#pragma unroll
            for (int ks = 0; ks < 2; ks++) READ_B(bv1[tj][ks], buf, 1, tj, ks);
        if (k + 1 < NK) STAGE_A(nbuf, 1, kA);
        BAR(); WAIT_LGKM0();
        __builtin_amdgcn_s_setprio(1);
#pragma unroll
        for (int ks = 0; ks < 2; ks++)
#pragma unroll
            for (int ti = 0; ti < 4; ti++)
#pragma unroll
                for (int tj = 0; tj < 2; tj++)
                    acc[ti][2 + tj] = __builtin_amdgcn_mfma_f32_16x16x32_bf16(
                        a[ti][ks], bv1[tj][ks], acc[ti][2 + tj], 0, 0, 0);
        __builtin_amdgcn_s_setprio(0);
        __builtin_amdgcn_sched_barrier(0);
        BAR();

        // ---- phase 2: (mh1, nh1); 8 ds_reads; stage B0(k+2) in-place
#pragma unroll
        for (int ti = 0; ti < 4; ti++)
#pragma unroll
            for (int ks = 0; ks < 2; ks++) READ_A(a[ti][ks], buf, 1, ti, ks);
        if (k + 2 < NK) STAGE_B(buf, 0, kB);
        BAR(); WAIT_LGKM0();
        __builtin_amdgcn_s_setprio(1);
#pragma unroll
        for (int ks = 0; ks < 2; ks++)
#pragma unroll
            for (int ti = 0; ti < 4; ti++)
#pragma unroll
                for (int tj = 0; tj < 2; tj++)
                    acc[4 + ti][2 + tj] = __builtin_amdgcn_mfma_f32_16x16x32_bf16(
                        a[ti][ks], bv1[tj][ks], acc[4 + ti][2 + tj], 0, 0, 0);
        __builtin_amdgcn_s_setprio(0);
        __builtin_amdgcn_sched_barrier(0);
        BAR();

        // ---- phase 3: (mh1, nh0); 0 ds_reads (bv0 live since ph0); stage B1(k+2)
        if (k + 2 < NK) STAGE_B(buf, 1, kB);
        BAR();
        __builtin_amdgcn_s_setprio(1);
#pragma unroll
        for (int ks = 0; ks < 2; ks++)
#pragma unroll
            for (int ti = 0; ti < 4; ti++)
#pragma unroll
                for (int tj = 0; tj < 2; tj++)
                    acc[4 + ti][tj] = __builtin_amdgcn_mfma_f32_16x16x32_bf16(
                        a[ti][ks], bv0[tj][ks], acc[4 + ti][tj], 0, 0, 0);
        __builtin_amdgcn_s_setprio(0);
        __builtin_amdgcn_sched_barrier(0);
        // ---- K-tile boundary: counted drain (see ledger comment above)
        if (k + 2 < NK) { WAIT_VM(4); } else { WAIT_VM(0); }
        BAR();
    }

#undef STAGE_A
#undef STAGE_B
#undef READ_A
#undef READ_B

    // epilogue: C/D layout col = lane&15, row = quad*4 + reg
#pragma unroll
    for (int mi = 0; mi < 8; mi++) {
        const int rloc = wm + (mi >> 2) * 64 + (mi & 3) * 16 + quad * 4;
#pragma unroll
        for (int nj = 0; nj < 4; nj++) {
            const int gcol = n0 + wn + (nj >> 1) * 32 + (nj & 1) * 16 + lrow;
            const float bb = be[gcol];
#pragma unroll
            for (int r = 0; r < 4; r++) {
                const int grow = rb * 256 + rloc + r;
                if (grow < Ne) {
                    float v = acc[mi][nj][r] + bb;
                    if (RELU) v = v > 0.f ? v : 0.f;
                    Out[(size_t)(base + grow) * ND + gcol] = (bf16)v;
                }
            }
        }
    }
}

// ---------------------------------------------------------------- combine
__global__ void combine_kernel(const bf16* __restrict__ Yb, const int* __restrict__ slot,
                               const float* __restrict__ wgt, float* __restrict__ out) {
    int t = blockIdx.x;
    int d = threadIdx.x * 4;
    int s0 = slot[t * 2], s1 = slot[t * 2 + 1];
    float w0 = wgt[t * 2], w1 = wgt[t * 2 + 1];
    bf16x4 y0 = *(const bf16x4*)(Yb + (size_t)s0 * D_DIM + d);
    bf16x4 y1 = *(const bf16x4*)(Yb + (size_t)s1 * D_DIM + d);
    float4 o;
    o.x = w0 * (float)y0[0] + w1 * (float)y1[0];
    o.y = w0 * (float)y0[1] + w1 * (float)y1[1];
    o.z = w0 * (float)y0[2] + w1 * (float)y1[2];
    o.w = w0 * (float)y0[3] + w1 * (float)y1[3];
    *(float4*)(out + (size_t)t * D_DIM + d) = o;
}

// ---------------------------------------------------------------- launch
extern "C" void kernel_launch(void* const* d_in, const int* in_sizes, int n_in,
                              void* d_out, int out_size, void* d_ws, size_t ws_size,
                              hipStream_t stream) {
    const float* x  = (const float*)d_in[0];
    const float* gw = (const float*)d_in[1];
    const float* gb = (const float*)d_in[2];
    const float* w1 = (const float*)d_in[3];
    const float* b1 = (const float*)d_in[4];
    const float* w2 = (const float*)d_in[5];
    const float* b2 = (const float*)d_in[6];
    float* out = (float*)d_out;

    char* ws = (char*)d_ws;
    // layout:
    //   [0,96)            counts[8] / fill[8] / offsets[8]
    //   [256, +4*64K)     eIdx, wgt, slot, rowIdx
    //   @262400           Xb   bf16 T*D               (16 MiB)
    //   @17039616         Hb   bf16 T*2*H             (64 MiB)
    //   @84148480         W2t  bf16 E*D*H             (32 MiB)
    //   @117702912        W1t  bf16 E*H*D  (aliases Yb: W1t dead after GEMM1,
    //                     Yb written by GEMM2)        (32 MiB)
    int*   counts = (int*)ws;
    int*   fill   = (int*)(ws + 32);
    int*   offs   = (int*)(ws + 64);
    int*   eIdx   = (int*)(ws + 256);
    float* wgt    = (float*)(ws + 256 + 65536);
    int*   slot   = (int*)(ws + 256 + 2 * 65536);
    int*   rowIdx = (int*)(ws + 256 + 3 * 65536);
    bf16*  Xb  = (bf16*)(ws + 262400);
    bf16*  Hb  = (bf16*)(ws + 17039616);
    bf16*  W2t = (bf16*)(ws + 84148480);
    bf16*  W1t = (bf16*)(ws + 117702912);
    bf16*  Yb  = W1t;  // alias (see above)

    if (ws_size < (size_t)151257344) return;

    hipMemsetAsync(ws, 0, 64, stream);  // counts + fill
    // w1 [E][D][H] -> W1t [E][H][D];  w2 [E][H][D] -> W2t [E][D][H]
    transpose_kernel<D_DIM, H_DIM>
        <<<dim3(H_DIM / 32, D_DIM / 32, E_NUM), 256, 0, stream>>>(w1, W1t);
    transpose_kernel<H_DIM, D_DIM>
        <<<dim3(D_DIM / 32, H_DIM / 32, E_NUM), 256, 0, stream>>>(w2, W2t);
    gating_kernel<<<T_TOK / 4, 256, 0, stream>>>(x, gw, gb, Xb, eIdx, wgt);
    count_kernel<<<T_TOK * 2 / 512, 256, 0, stream>>>(eIdx, counts);
    scan_kernel<<<1, 64, 0, stream>>>(counts, offs);
    scatter_kernel<<<T_TOK / 512, 256, 0, stream>>>(eIdx, offs, fill, rowIdx, slot);
    // GEMM1: h = relu(x_gathered @ W1 + b1)   [rows, 2048], K=1024
    moe_gemm256_kernel<D_DIM, H_DIM, true, true>
        <<<dim3(H_DIM / 256, T_TOK / 256, E_NUM), 512, 0, stream>>>(
            Xb, W1t, b1, Hb, counts, offs, rowIdx);
    // GEMM2: y = h @ W2 + b2   [rows, 1024], K=2048
    moe_gemm256_kernel<H_DIM, D_DIM, false, false>
        <<<dim3(D_DIM / 256, T_TOK / 256, E_NUM), 512, 0, stream>>>(
            Hb, W2t, b2, Yb, counts, offs, (const int*)nullptr);
    combine_kernel<<<T_TOK, 256, 0, stream>>>(Yb, slot, wgt, out);
}